// Round 1
// baseline (707.780 us; speedup 1.0000x reference)
//
#include <hip/hip_runtime.h>
#include <hip/hip_bf16.h>
#include <cstdint>

#define BATCH 8
#define SEQ   2048
#define DIM   256
#define NN    ((size_t)SEQ * SEQ)   // 4194304 per batch
#define ND    ((size_t)SEQ * DIM)   // 524288 per batch

typedef __hip_bfloat16 bf16;
typedef __attribute__((ext_vector_type(8))) short bf16x8;
typedef __attribute__((ext_vector_type(4))) float f32x4;

// async global->LDS, 16B per lane; LDS dest = wave-uniform base + lane*16
__device__ __forceinline__ void async16(const void* g, void* l) {
    __builtin_amdgcn_global_load_lds(
        (__attribute__((address_space(1))) unsigned int*)(uintptr_t)g,
        (__attribute__((address_space(3))) unsigned int*)(uintptr_t)l,
        16, 0, 0);
}

// ---------------------------------------------------------------------------
// adj [B][N][N] f32  ->  adjT [B][N][N] bf16, adjT[b][j][i] = adj[b][i][j]
// ---------------------------------------------------------------------------
__global__ __launch_bounds__(256) void transpose_adj_kernel(
        const float* __restrict__ adj, bf16* __restrict__ adjT) {
    __shared__ float tile[32][33];
    const int b  = blockIdx.z;
    const int i0 = blockIdx.y << 5;
    const int j0 = blockIdx.x << 5;
    const float* src = adj + (size_t)b * NN;
    bf16* dst = adjT + (size_t)b * NN;
    const int tx = threadIdx.x & 31;
    const int ty = threadIdx.x >> 5;
    #pragma unroll
    for (int r = ty; r < 32; r += 8)
        tile[r][tx] = src[(size_t)(i0 + r) * SEQ + j0 + tx];
    __syncthreads();
    #pragma unroll
    for (int r = ty; r < 32; r += 8)
        dst[(size_t)(j0 + r) * SEQ + i0 + tx] = __float2bfloat16(tile[tx][r]);
}

// ---------------------------------------------------------------------------
// v [B][N][D] bf16 -> vT [B][D][N] bf16
// ---------------------------------------------------------------------------
__global__ __launch_bounds__(256) void transpose_v_kernel(
        const bf16* __restrict__ v, bf16* __restrict__ vT) {
    __shared__ bf16 tile[32][33];
    const int b  = blockIdx.z;
    const int i0 = blockIdx.y << 5;   // row in v (0..2047)
    const int j0 = blockIdx.x << 5;   // col in v (0..255)
    const bf16* src = v + (size_t)b * ND;
    bf16* dst = vT + (size_t)b * ND;
    const int tx = threadIdx.x & 31;
    const int ty = threadIdx.x >> 5;
    #pragma unroll
    for (int r = ty; r < 32; r += 8)
        tile[r][tx] = src[(size_t)(i0 + r) * DIM + j0 + tx];
    __syncthreads();
    #pragma unroll
    for (int r = ty; r < 32; r += 8)
        dst[(size_t)(j0 + r) * SEQ + i0 + tx] = tile[tx][r];
}

// ---------------------------------------------------------------------------
// q/k/v = text @ W + b  (fp32 accum, bf16 out). 16 rows per block.
// ---------------------------------------------------------------------------
__global__ __launch_bounds__(256) void qkv_kernel(
        const float* __restrict__ text,
        const float* __restrict__ Wq, const float* __restrict__ bq,
        const float* __restrict__ Wk, const float* __restrict__ bk,
        const float* __restrict__ Wv, const float* __restrict__ bv,
        bf16* __restrict__ q, bf16* __restrict__ k, bf16* __restrict__ v) {
    __shared__ float xs[16][DIM];
    const size_t row0 = (size_t)blockIdx.x * 16;
    const int o = threadIdx.x;
    #pragma unroll
    for (int r = 0; r < 16; ++r)
        xs[r][o] = text[(row0 + r) * DIM + o];
    __syncthreads();
    float aq[16], ak[16], av[16];
    const float cq = bq[o], ck = bk[o], cv = bv[o];
    #pragma unroll
    for (int r = 0; r < 16; ++r) { aq[r] = cq; ak[r] = ck; av[r] = cv; }
    for (int i = 0; i < DIM; ++i) {
        const float wq = Wq[i * DIM + o];
        const float wk = Wk[i * DIM + o];
        const float wv = Wv[i * DIM + o];
        #pragma unroll
        for (int r = 0; r < 16; ++r) {
            const float x = xs[r][i];
            aq[r] = fmaf(x, wq, aq[r]);
            ak[r] = fmaf(x, wk, ak[r]);
            av[r] = fmaf(x, wv, av[r]);
        }
    }
    #pragma unroll
    for (int r = 0; r < 16; ++r) {
        q[(row0 + r) * DIM + o] = __float2bfloat16(aq[r]);
        k[(row0 + r) * DIM + o] = __float2bfloat16(ak[r]);
        v[(row0 + r) * DIM + o] = __float2bfloat16(av[r]);
    }
}

// ---------------------------------------------------------------------------
// C[b] = scale * (A[b] @ Bt[b]^T); A:[M][K], Bt:[Ncols][K] (both bf16 row-major)
// optional fp32 and bf16 outputs. 128x128 tile, 4 waves of 4x4 16x16x32 MFMAs.
// M, Ncols multiples of 128; K multiple of 32.
// ---------------------------------------------------------------------------
__global__ __launch_bounds__(256) void gemm_bt(
        const bf16* __restrict__ A, const bf16* __restrict__ Bt,
        float* __restrict__ Cf, bf16* __restrict__ Cb,
        int M, int Ncols, int K,
        long long sA, long long sB, long long sCf, long long sCb,
        float scale) {
    __shared__ bf16 As[128 * 32];
    __shared__ bf16 Bs[128 * 32];
    const int bz = blockIdx.z;
    const bf16* Ab = A  + (size_t)bz * sA;
    const bf16* Bb = Bt + (size_t)bz * sB;
    const int row0 = blockIdx.x << 7;
    const int col0 = blockIdx.y << 7;
    const int tid  = threadIdx.x;
    const int wave = tid >> 6;
    const int lane = tid & 63;
    const int wr0 = (wave >> 1) << 6;   // wave row offset within tile
    const int wc0 = (wave & 1) << 6;    // wave col offset
    const int fl = lane & 15;
    const int fq = lane >> 4;
    // staging: chunk c = wave*2+i covers rows [c*16, c*16+16), 64 lanes x 16B
    const int c0  = wave * 2;
    const int sr  = c0 * 16 + (lane >> 2);
    const int sk  = (lane & 3) * 8;

    f32x4 acc[4][4] = {};

    for (int k0 = 0; k0 < K; k0 += 32) {
        async16(Ab + (size_t)(row0 + sr)      * K + k0 + sk, As + (c0    ) * 512);
        async16(Ab + (size_t)(row0 + sr + 16) * K + k0 + sk, As + (c0 + 1) * 512);
        async16(Bb + (size_t)(col0 + sr)      * K + k0 + sk, Bs + (c0    ) * 512);
        async16(Bb + (size_t)(col0 + sr + 16) * K + k0 + sk, Bs + (c0 + 1) * 512);
        __syncthreads();
        bf16x8 af[4], bg[4];
        #pragma unroll
        for (int i = 0; i < 4; ++i) {
            af[i] = *(const bf16x8*)(As + (wr0 + i * 16 + fl) * 32 + fq * 8);
            bg[i] = *(const bf16x8*)(Bs + (wc0 + i * 16 + fl) * 32 + fq * 8);
        }
        #pragma unroll
        for (int i = 0; i < 4; ++i)
            #pragma unroll
            for (int j = 0; j < 4; ++j)
                acc[i][j] = __builtin_amdgcn_mfma_f32_16x16x32_bf16(
                    af[i], bg[j], acc[i][j], 0, 0, 0);
        __syncthreads();
    }

    // C/D layout: col = lane&15, row = (lane>>4)*4 + reg
    #pragma unroll
    for (int i = 0; i < 4; ++i) {
        #pragma unroll
        for (int j = 0; j < 4; ++j) {
            #pragma unroll
            for (int r = 0; r < 4; ++r) {
                const int row = row0 + wr0 + i * 16 + fq * 4 + r;
                const int col = col0 + wc0 + j * 16 + fl;
                const float val = acc[i][j][r] * scale;
                if (Cf) Cf[(size_t)bz * sCf + (size_t)row * Ncols + col] = val;
                if (Cb) Cb[(size_t)bz * sCb + (size_t)row * Ncols + col] =
                    __float2bfloat16(val);
            }
        }
    }
}

// ---------------------------------------------------------------------------
// in-place row softmax over bf16 rows of length SEQ (one block per row)
// ---------------------------------------------------------------------------
__global__ __launch_bounds__(256) void softmax_rows(bf16* __restrict__ S) {
    __shared__ float red[4];
    bf16* p = S + (size_t)blockIdx.x * SEQ;
    const int t = threadIdx.x;
    float x[8];
    #pragma unroll
    for (int j = 0; j < 8; ++j) x[j] = __bfloat162float(p[t + 256 * j]);
    float m = x[0];
    #pragma unroll
    for (int j = 1; j < 8; ++j) m = fmaxf(m, x[j]);
    #pragma unroll
    for (int off = 32; off >= 1; off >>= 1) m = fmaxf(m, __shfl_xor(m, off, 64));
    if ((t & 63) == 0) red[t >> 6] = m;
    __syncthreads();
    m = fmaxf(fmaxf(red[0], red[1]), fmaxf(red[2], red[3]));
    __syncthreads();
    float s = 0.f;
    #pragma unroll
    for (int j = 0; j < 8; ++j) { x[j] = __expf(x[j] - m); s += x[j]; }
    #pragma unroll
    for (int off = 32; off >= 1; off >>= 1) s += __shfl_xor(s, off, 64);
    if ((t & 63) == 0) red[t >> 6] = s;
    __syncthreads();
    s = red[0] + red[1] + red[2] + red[3];
    const float inv = 1.0f / s;
    #pragma unroll
    for (int j = 0; j < 8; ++j)
        p[t + 256 * j] = __float2bfloat16(x[j] * inv);
}

// ---------------------------------------------------------------------------
extern "C" void kernel_launch(void* const* d_in, const int* in_sizes, int n_in,
                              void* d_out, int out_size, void* d_ws, size_t ws_size,
                              hipStream_t stream) {
    (void)in_sizes; (void)n_in; (void)out_size; (void)ws_size;
    const float* text = (const float*)d_in[0];
    const float* adj  = (const float*)d_in[1];
    const float* Wq   = (const float*)d_in[2];
    const float* bq   = (const float*)d_in[3];
    const float* Wk   = (const float*)d_in[4];
    const float* bk   = (const float*)d_in[5];
    const float* Wv   = (const float*)d_in[6];
    const float* bv   = (const float*)d_in[7];

    float* out0 = (float*)d_out;                 // output [B,N,D]
    float* out1 = out0 + (size_t)BATCH * ND;     // new_adj [B,N,N]

    bf16* w = (bf16*)d_ws;
    bf16* adjT = w;  w += BATCH * NN;
    bf16* qb   = w;  w += BATCH * ND;
    bf16* kb   = w;  w += BATCH * ND;
    bf16* vb   = w;  w += BATCH * ND;
    bf16* vTb  = w;  w += BATCH * ND;
    bf16* attn = w;  w += BATCH * NN;   // scores, then softmax in place
    bf16* nadj = w;  w += BATCH * NN;

    transpose_adj_kernel<<<dim3(64, 64, BATCH), 256, 0, stream>>>(adj, adjT);
    qkv_kernel<<<dim3(BATCH * SEQ / 16), 256, 0, stream>>>(
        text, Wq, bq, Wk, bk, Wv, bv, qb, kb, vb);
    transpose_v_kernel<<<dim3(8, 64, BATCH), 256, 0, stream>>>(vb, vTb);
    // scores = (q @ k^T) / 16  -> bf16
    gemm_bt<<<dim3(16, 16, BATCH), 256, 0, stream>>>(
        qb, kb, nullptr, attn, SEQ, SEQ, DIM,
        (long long)ND, (long long)ND, 0, (long long)NN, 1.0f / 16.0f);
    softmax_rows<<<dim3(BATCH * SEQ), 256, 0, stream>>>(attn);
    // new_adj = attn @ adj  -> fp32 (d_out) + bf16 (ws)
    gemm_bt<<<dim3(16, 16, BATCH), 256, 0, stream>>>(
        attn, adjT, out1, nadj, SEQ, SEQ, SEQ,
        (long long)NN, (long long)NN, (long long)NN, (long long)NN, 1.0f);
    // output = new_adj @ v  -> fp32 (d_out)
    gemm_bt<<<dim3(16, 2, BATCH), 256, 0, stream>>>(
        nadj, vTb, out0, nullptr, SEQ, DIM, SEQ,
        (long long)NN, (long long)ND, (long long)ND, 0, 1.0f);
}

// Round 2
// 705.189 us; speedup vs baseline: 1.0037x; 1.0037x over previous
//
#include <hip/hip_runtime.h>
#include <hip/hip_bf16.h>
#include <cstdint>

#define BATCH 8
#define SEQ   2048
#define DIM   256
#define NN    ((size_t)SEQ * SEQ)   // 4194304 per batch
#define ND    ((size_t)SEQ * DIM)   // 524288 per batch

typedef __hip_bfloat16 bf16;
typedef __attribute__((ext_vector_type(8))) short bf16x8;
typedef __attribute__((ext_vector_type(4))) float f32x4;

// async global->LDS, 16B per lane; LDS dest = wave-uniform base + lane*16
__device__ __forceinline__ void async16(const void* g, void* l) {
    __builtin_amdgcn_global_load_lds(
        (__attribute__((address_space(1))) unsigned int*)(uintptr_t)g,
        (__attribute__((address_space(3))) unsigned int*)(uintptr_t)l,
        16, 0, 0);
}

// ---------------------------------------------------------------------------
// adj [B][N][N] f32  ->  adjT [B][N][N] bf16
// ---------------------------------------------------------------------------
__global__ __launch_bounds__(256) void transpose_adj_kernel(
        const float* __restrict__ adj, bf16* __restrict__ adjT) {
    __shared__ float tile[32][33];
    const int b  = blockIdx.z;
    const int i0 = blockIdx.y << 5;
    const int j0 = blockIdx.x << 5;
    const float* src = adj + (size_t)b * NN;
    bf16* dst = adjT + (size_t)b * NN;
    const int tx = threadIdx.x & 31;
    const int ty = threadIdx.x >> 5;
    #pragma unroll
    for (int r = ty; r < 32; r += 8)
        tile[r][tx] = src[(size_t)(i0 + r) * SEQ + j0 + tx];
    __syncthreads();
    #pragma unroll
    for (int r = ty; r < 32; r += 8)
        dst[(size_t)(j0 + r) * SEQ + i0 + tx] = __float2bfloat16(tile[tx][r]);
}

// ---------------------------------------------------------------------------
// v [B][N][D] bf16 -> vT [B][D][N] bf16
// ---------------------------------------------------------------------------
__global__ __launch_bounds__(256) void transpose_v_kernel(
        const bf16* __restrict__ v, bf16* __restrict__ vT) {
    __shared__ bf16 tile[32][33];
    const int b  = blockIdx.z;
    const int i0 = blockIdx.y << 5;
    const int j0 = blockIdx.x << 5;
    const bf16* src = v + (size_t)b * ND;
    bf16* dst = vT + (size_t)b * ND;
    const int tx = threadIdx.x & 31;
    const int ty = threadIdx.x >> 5;
    #pragma unroll
    for (int r = ty; r < 32; r += 8)
        tile[r][tx] = src[(size_t)(i0 + r) * DIM + j0 + tx];
    __syncthreads();
    #pragma unroll
    for (int r = ty; r < 32; r += 8)
        dst[(size_t)(j0 + r) * SEQ + i0 + tx] = tile[tx][r];
}

// ---------------------------------------------------------------------------
// q/k/v = text @ W + b  (fp32 accum, bf16 out). 16 rows per block.
// ---------------------------------------------------------------------------
__global__ __launch_bounds__(256) void qkv_kernel(
        const float* __restrict__ text,
        const float* __restrict__ Wq, const float* __restrict__ bq,
        const float* __restrict__ Wk, const float* __restrict__ bk,
        const float* __restrict__ Wv, const float* __restrict__ bv,
        bf16* __restrict__ q, bf16* __restrict__ k, bf16* __restrict__ v) {
    __shared__ float xs[16][DIM];
    const size_t row0 = (size_t)blockIdx.x * 16;
    const int o = threadIdx.x;
    #pragma unroll
    for (int r = 0; r < 16; ++r)
        xs[r][o] = text[(row0 + r) * DIM + o];
    __syncthreads();
    float aq[16], ak[16], av[16];
    const float cq = bq[o], ck = bk[o], cv = bv[o];
    #pragma unroll
    for (int r = 0; r < 16; ++r) { aq[r] = cq; ak[r] = ck; av[r] = cv; }
    for (int i = 0; i < DIM; ++i) {
        const float wq = Wq[i * DIM + o];
        const float wk = Wk[i * DIM + o];
        const float wv = Wv[i * DIM + o];
        #pragma unroll
        for (int r = 0; r < 16; ++r) {
            const float x = xs[r][i];
            aq[r] = fmaf(x, wq, aq[r]);
            ak[r] = fmaf(x, wk, ak[r]);
            av[r] = fmaf(x, wv, av[r]);
        }
    }
    #pragma unroll
    for (int r = 0; r < 16; ++r) {
        q[(row0 + r) * DIM + o] = __float2bfloat16(aq[r]);
        k[(row0 + r) * DIM + o] = __float2bfloat16(ak[r]);
        v[(row0 + r) * DIM + o] = __float2bfloat16(av[r]);
    }
}

// ---------------------------------------------------------------------------
// C[b] = scale * (A[b] @ Bt[b]^T); A:[M][K], Bt:[Ncols][K] bf16 row-major.
// Templated tile: BM x BN, WR x WC waves (256 threads).
// LDS K-slot XOR swizzle: slot s at row r holds global kq = s ^ ((r%16)>>1)&3
// -> fragment ds_read_b128 lands 2-way on banks (free) instead of 8-way.
// ---------------------------------------------------------------------------
template <int BM, int BN, int WR, int WC>
__global__ __launch_bounds__(256) void gemm_bt(
        const bf16* __restrict__ A, const bf16* __restrict__ Bt,
        float* __restrict__ Cf, bf16* __restrict__ Cb,
        int M, int Ncols, int K,
        long long sA, long long sB, long long sCf, long long sCb,
        float scale) {
    constexpr int FI = BM / WR / 16;   // frags per wave, row dim
    constexpr int FJ = BN / WC / 16;   // frags per wave, col dim
    constexpr int CA = BM / 64;        // A staging chunks (4KB each)
    constexpr int CB = BN / 64;        // B staging chunks

    __shared__ bf16 As[BM * 32];
    __shared__ bf16 Bs[BN * 32];
    const int bz = blockIdx.z;
    const bf16* Ab = A  + (size_t)bz * sA;
    const bf16* Bb = Bt + (size_t)bz * sB;
    const int row0 = blockIdx.x * BM;
    const int col0 = blockIdx.y * BN;
    const int tid  = threadIdx.x;
    const int wave = tid >> 6;
    const int lane = tid & 63;
    const int wr0 = (wave / WC) * (BM / WR);
    const int wc0 = (wave % WC) * (BN / WC);
    const int fl = lane & 15;
    const int fq = lane >> 4;
    // staging mapping: chunk a: row = a*64 + tid/4, slot = tid&3,
    // global kq = slot ^ g(row%16), g(r) = (r>>1)&3
    const int srow = tid >> 2;
    const int sk   = ((tid & 3) ^ ((tid >> 3) & 3)) * 8;  // global k-offset (elems)
    // fragment read slot = fq ^ g(fl)
    const int slot = (fq ^ ((fl >> 1) & 3)) * 8;

    f32x4 acc[FI][FJ] = {};

    for (int k0 = 0; k0 < K; k0 += 32) {
        #pragma unroll
        for (int a = 0; a < CA; ++a)
            async16(Ab + (size_t)(row0 + a * 64 + srow) * K + k0 + sk,
                    As + a * 2048 + tid * 8);
        #pragma unroll
        for (int a = 0; a < CB; ++a)
            async16(Bb + (size_t)(col0 + a * 64 + srow) * K + k0 + sk,
                    Bs + a * 2048 + tid * 8);
        __syncthreads();
        bf16x8 af[FI], bg[FJ];
        #pragma unroll
        for (int i = 0; i < FI; ++i)
            af[i] = *(const bf16x8*)(As + (wr0 + i * 16 + fl) * 32 + slot);
        #pragma unroll
        for (int j = 0; j < FJ; ++j)
            bg[j] = *(const bf16x8*)(Bs + (wc0 + j * 16 + fl) * 32 + slot);
        #pragma unroll
        for (int i = 0; i < FI; ++i)
            #pragma unroll
            for (int j = 0; j < FJ; ++j)
                acc[i][j] = __builtin_amdgcn_mfma_f32_16x16x32_bf16(
                    af[i], bg[j], acc[i][j], 0, 0, 0);
        __syncthreads();
    }

    // C/D layout: col = lane&15, row = (lane>>4)*4 + reg
    #pragma unroll
    for (int i = 0; i < FI; ++i) {
        #pragma unroll
        for (int j = 0; j < FJ; ++j) {
            #pragma unroll
            for (int r = 0; r < 4; ++r) {
                const int row = row0 + wr0 + i * 16 + fq * 4 + r;
                const int col = col0 + wc0 + j * 16 + fl;
                const float val = acc[i][j][r] * scale;
                if (Cf) Cf[(size_t)bz * sCf + (size_t)row * Ncols + col] = val;
                if (Cb) Cb[(size_t)bz * sCb + (size_t)row * Ncols + col] =
                    __float2bfloat16(val);
            }
        }
    }
}

// ---------------------------------------------------------------------------
// in-place row softmax over bf16 rows of length SEQ (one block per row)
// ---------------------------------------------------------------------------
__global__ __launch_bounds__(256) void softmax_rows(bf16* __restrict__ S) {
    __shared__ float red[4];
    bf16* p = S + (size_t)blockIdx.x * SEQ;
    const int t = threadIdx.x;
    float x[8];
    #pragma unroll
    for (int j = 0; j < 8; ++j) x[j] = __bfloat162float(p[t + 256 * j]);
    float m = x[0];
    #pragma unroll
    for (int j = 1; j < 8; ++j) m = fmaxf(m, x[j]);
    #pragma unroll
    for (int off = 32; off >= 1; off >>= 1) m = fmaxf(m, __shfl_xor(m, off, 64));
    if ((t & 63) == 0) red[t >> 6] = m;
    __syncthreads();
    m = fmaxf(fmaxf(red[0], red[1]), fmaxf(red[2], red[3]));
    __syncthreads();
    float s = 0.f;
    #pragma unroll
    for (int j = 0; j < 8; ++j) { x[j] = __expf(x[j] - m); s += x[j]; }
    #pragma unroll
    for (int off = 32; off >= 1; off >>= 1) s += __shfl_xor(s, off, 64);
    if ((t & 63) == 0) red[t >> 6] = s;
    __syncthreads();
    s = red[0] + red[1] + red[2] + red[3];
    const float inv = 1.0f / s;
    #pragma unroll
    for (int j = 0; j < 8; ++j)
        p[t + 256 * j] = __float2bfloat16(x[j] * inv);
}

// ---------------------------------------------------------------------------
extern "C" void kernel_launch(void* const* d_in, const int* in_sizes, int n_in,
                              void* d_out, int out_size, void* d_ws, size_t ws_size,
                              hipStream_t stream) {
    (void)in_sizes; (void)n_in; (void)out_size; (void)ws_size;
    const float* text = (const float*)d_in[0];
    const float* adj  = (const float*)d_in[1];
    const float* Wq   = (const float*)d_in[2];
    const float* bq   = (const float*)d_in[3];
    const float* Wk   = (const float*)d_in[4];
    const float* bk   = (const float*)d_in[5];
    const float* Wv   = (const float*)d_in[6];
    const float* bv   = (const float*)d_in[7];

    float* out0 = (float*)d_out;                 // output [B,N,D]
    float* out1 = out0 + (size_t)BATCH * ND;     // new_adj [B,N,N]

    bf16* w = (bf16*)d_ws;
    bf16* adjT = w;  w += BATCH * NN;
    bf16* qb   = w;  w += BATCH * ND;
    bf16* kb   = w;  w += BATCH * ND;
    bf16* vb   = w;  w += BATCH * ND;
    bf16* vTb  = w;  w += BATCH * ND;
    bf16* attn = w;  w += BATCH * NN;   // scores, then softmax in place
    bf16* nadj = w;  w += BATCH * NN;

    transpose_adj_kernel<<<dim3(64, 64, BATCH), 256, 0, stream>>>(adj, adjT);
    qkv_kernel<<<dim3(BATCH * SEQ / 16), 256, 0, stream>>>(
        text, Wq, bq, Wk, bk, Wv, bv, qb, kb, vb);
    transpose_v_kernel<<<dim3(8, 64, BATCH), 256, 0, stream>>>(vb, vTb);
    // scores = (q @ k^T) / 16  -> bf16
    gemm_bt<128, 128, 2, 2><<<dim3(16, 16, BATCH), 256, 0, stream>>>(
        qb, kb, nullptr, attn, SEQ, SEQ, DIM,
        (long long)ND, (long long)ND, 0, (long long)NN, 1.0f / 16.0f);
    softmax_rows<<<dim3(BATCH * SEQ), 256, 0, stream>>>(attn);
    // new_adj = attn @ adj  -> fp32 (d_out) + bf16 (ws)
    gemm_bt<128, 128, 2, 2><<<dim3(16, 16, BATCH), 256, 0, stream>>>(
        attn, adjT, out1, nadj, SEQ, SEQ, SEQ,
        (long long)NN, (long long)NN, (long long)NN, (long long)NN, 1.0f);
    // output = new_adj @ v  -> fp32 (d_out); 128x64 tile => 512 blocks
    gemm_bt<128, 64, 4, 1><<<dim3(16, 4, BATCH), 256, 0, stream>>>(
        nadj, vTb, out0, nullptr, SEQ, DIM, SEQ,
        (long long)NN, (long long)ND, (long long)ND, 0, 1.0f);
}

// Round 3
// 698.477 us; speedup vs baseline: 1.0133x; 1.0096x over previous
//
#include <hip/hip_runtime.h>
#include <hip/hip_bf16.h>
#include <cstdint>

#define BATCH 8
#define SEQ   2048
#define DIM   256
#define NN    ((size_t)SEQ * SEQ)   // 4194304 per batch
#define ND    ((size_t)SEQ * DIM)   // 524288 per batch

typedef __hip_bfloat16 bf16;
typedef __attribute__((ext_vector_type(8))) short bf16x8;
typedef __attribute__((ext_vector_type(4))) short bf16x4;
typedef __attribute__((ext_vector_type(4))) float f32x4;

__device__ __forceinline__ short bfbits(float f) {
    bf16 b = __float2bfloat16(f);
    return *reinterpret_cast<short*>(&b);
}
__device__ __forceinline__ float bf2f(short s) {
    bf16 b = *reinterpret_cast<bf16*>(&s);
    return __bfloat162float(b);
}

// async global->LDS, 16B per lane; LDS dest = wave-uniform base + lane*16
__device__ __forceinline__ void async16(const void* g, void* l) {
    __builtin_amdgcn_global_load_lds(
        (__attribute__((address_space(1))) unsigned int*)(uintptr_t)g,
        (__attribute__((address_space(3))) unsigned int*)(uintptr_t)l,
        16, 0, 0);
}

// ---------------------------------------------------------------------------
// adj [B][N][N] f32 -> adjT [B][N][N] bf16. 64x64 tile, float4 loads,
// bf16x4 (8B) stores. tile stride 67 -> <=2-way LDS banks both sides.
// ---------------------------------------------------------------------------
__global__ __launch_bounds__(256) void transpose_adj_kernel(
        const float* __restrict__ adj, bf16* __restrict__ adjT) {
    __shared__ float tile[64][67];
    const int b  = blockIdx.z;
    const int i0 = blockIdx.y << 6;
    const int j0 = blockIdx.x << 6;
    const float* src = adj + (size_t)b * NN;
    bf16* dst = adjT + (size_t)b * NN;
    const int r  = threadIdx.x >> 4;        // 0..15
    const int c4 = (threadIdx.x & 15) << 2; // 0..60 step 4
    #pragma unroll
    for (int p = 0; p < 4; ++p) {
        const int row = r + p * 16;
        const float4 v = *(const float4*)(src + (size_t)(i0 + row) * SEQ + j0 + c4);
        tile[row][c4 + 0] = v.x;
        tile[row][c4 + 1] = v.y;
        tile[row][c4 + 2] = v.z;
        tile[row][c4 + 3] = v.w;
    }
    __syncthreads();
    #pragma unroll
    for (int p = 0; p < 4; ++p) {
        const int jj = r + p * 16;
        bf16x4 o;
        o[0] = bfbits(tile[c4 + 0][jj]);
        o[1] = bfbits(tile[c4 + 1][jj]);
        o[2] = bfbits(tile[c4 + 2][jj]);
        o[3] = bfbits(tile[c4 + 3][jj]);
        *(bf16x4*)(dst + (size_t)(j0 + jj) * SEQ + i0 + c4) = o;
    }
}

// ---------------------------------------------------------------------------
// q/k = text @ W + b (bf16, row-major); v written TRANSPOSED: vT[o][row].
// ---------------------------------------------------------------------------
__global__ __launch_bounds__(256) void qkv_kernel(
        const float* __restrict__ text,
        const float* __restrict__ Wq, const float* __restrict__ bq,
        const float* __restrict__ Wk, const float* __restrict__ bk,
        const float* __restrict__ Wv, const float* __restrict__ bv,
        bf16* __restrict__ q, bf16* __restrict__ k, bf16* __restrict__ vT) {
    __shared__ float xs[16][DIM];
    const size_t row0 = (size_t)blockIdx.x * 16;
    const size_t brow = row0 % SEQ;                 // row within batch
    const size_t bIdx = row0 / SEQ;                 // batch index
    const int o = threadIdx.x;
    #pragma unroll
    for (int r = 0; r < 16; ++r)
        xs[r][o] = text[(row0 + r) * DIM + o];
    __syncthreads();
    float aq[16], ak[16], av[16];
    const float cq = bq[o], ck = bk[o], cv = bv[o];
    #pragma unroll
    for (int r = 0; r < 16; ++r) { aq[r] = cq; ak[r] = ck; av[r] = cv; }
    for (int i = 0; i < DIM; ++i) {
        const float wq = Wq[i * DIM + o];
        const float wk = Wk[i * DIM + o];
        const float wv = Wv[i * DIM + o];
        #pragma unroll
        for (int r = 0; r < 16; ++r) {
            const float x = xs[r][i];
            aq[r] = fmaf(x, wq, aq[r]);
            ak[r] = fmaf(x, wk, ak[r]);
            av[r] = fmaf(x, wv, av[r]);
        }
    }
    #pragma unroll
    for (int r = 0; r < 16; ++r) {
        q[(row0 + r) * DIM + o] = __float2bfloat16(aq[r]);
        k[(row0 + r) * DIM + o] = __float2bfloat16(ak[r]);
    }
    bf16x8 t0, t1;
    #pragma unroll
    for (int r = 0; r < 8; ++r) { t0[r] = bfbits(av[r]); t1[r] = bfbits(av[8 + r]); }
    bf16* vrow = vT + bIdx * ND + (size_t)o * SEQ + brow;
    *(bf16x8*)(vrow)     = t0;
    *(bf16x8*)(vrow + 8) = t1;
}

// ---------------------------------------------------------------------------
// C[b] = scale * (A[b] @ Bt[b]^T); A:[M][K], Bt:[Ncols][K] bf16 row-major.
// BK=64 K-loop (half the barriers of BK=32). LDS slot swizzle:
// phys slot p at row r holds logical k-slot p^(r&7) (16B slots) ->
// staging stays lane-contiguous, fragment ds_read_b128 is 2-way (free).
// ---------------------------------------------------------------------------
template <int BM, int BN, int WR, int WC>
__global__ __launch_bounds__(256) void gemm_bt(
        const bf16* __restrict__ A, const bf16* __restrict__ Bt,
        float* __restrict__ Cf, bf16* __restrict__ Cb,
        int M, int Ncols, int K,
        long long sA, long long sB, long long sCf, long long sCb,
        float scale) {
    constexpr int FI = BM / WR / 16;   // frags per wave, row dim
    constexpr int FJ = BN / WC / 16;   // frags per wave, col dim
    constexpr int CA = BM / 32;        // staging chunks (32 rows x 64k each)
    constexpr int CB = BN / 32;

    __shared__ bf16 As[BM * 64];
    __shared__ bf16 Bs[BN * 64];
    const int bz = blockIdx.z;
    const bf16* Ab = A  + (size_t)bz * sA;
    const bf16* Bb = Bt + (size_t)bz * sB;
    const int row0 = blockIdx.x * BM;
    const int col0 = blockIdx.y * BN;
    const int tid  = threadIdx.x;
    const int wave = tid >> 6;
    const int lane = tid & 63;
    const int wr0 = (wave / WC) * (BM / WR);
    const int wc0 = (wave % WC) * (BN / WC);
    const int fl = lane & 15;
    const int fq = lane >> 4;
    // staging: chunk a, row = a*32 + tid/8, phys slot = tid&7,
    // global k-offset = (slot ^ (row&7))*8
    const int srow = tid >> 3;
    const int sk   = ((tid & 7) ^ (srow & 7)) * 8;

    f32x4 acc[FI][FJ] = {};

    for (int k0 = 0; k0 < K; k0 += 64) {
        #pragma unroll
        for (int a = 0; a < CA; ++a)
            async16(Ab + (size_t)(row0 + a * 32 + srow) * K + k0 + sk,
                    As + a * 2048 + tid * 8);
        #pragma unroll
        for (int a = 0; a < CB; ++a)
            async16(Bb + (size_t)(col0 + a * 32 + srow) * K + k0 + sk,
                    Bs + a * 2048 + tid * 8);
        __syncthreads();
        #pragma unroll
        for (int m = 0; m < 2; ++m) {
            const int p = ((m * 4 + fq) ^ (fl & 7)) * 8;
            bf16x8 af[FI], bg[FJ];
            #pragma unroll
            for (int i = 0; i < FI; ++i)
                af[i] = *(const bf16x8*)(As + (wr0 + i * 16 + fl) * 64 + p);
            #pragma unroll
            for (int j = 0; j < FJ; ++j)
                bg[j] = *(const bf16x8*)(Bs + (wc0 + j * 16 + fl) * 64 + p);
            #pragma unroll
            for (int i = 0; i < FI; ++i)
                #pragma unroll
                for (int j = 0; j < FJ; ++j)
                    acc[i][j] = __builtin_amdgcn_mfma_f32_16x16x32_bf16(
                        af[i], bg[j], acc[i][j], 0, 0, 0);
        }
        __syncthreads();
    }

    // C/D layout: col = lane&15, row = (lane>>4)*4 + reg
    #pragma unroll
    for (int i = 0; i < FI; ++i) {
        #pragma unroll
        for (int j = 0; j < FJ; ++j) {
            #pragma unroll
            for (int r = 0; r < 4; ++r) {
                const int row = row0 + wr0 + i * 16 + fq * 4 + r;
                const int col = col0 + wc0 + j * 16 + fl;
                const float val = acc[i][j][r] * scale;
                if (Cf) Cf[(size_t)bz * sCf + (size_t)row * Ncols + col] = val;
                if (Cb) Cb[(size_t)bz * sCb + (size_t)row * Ncols + col] =
                    __float2bfloat16(val);
            }
        }
    }
}

// ---------------------------------------------------------------------------
// in-place row softmax, bf16 rows of length SEQ; 16B vector load/store
// ---------------------------------------------------------------------------
__global__ __launch_bounds__(256) void softmax_rows(bf16* __restrict__ S) {
    __shared__ float red[4];
    bf16* p = S + (size_t)blockIdx.x * SEQ;
    const int t = threadIdx.x;
    bf16x8 v8 = *(const bf16x8*)(p + t * 8);
    float x[8];
    #pragma unroll
    for (int j = 0; j < 8; ++j) x[j] = bf2f(v8[j]);
    float m = x[0];
    #pragma unroll
    for (int j = 1; j < 8; ++j) m = fmaxf(m, x[j]);
    #pragma unroll
    for (int off = 32; off >= 1; off >>= 1) m = fmaxf(m, __shfl_xor(m, off, 64));
    if ((t & 63) == 0) red[t >> 6] = m;
    __syncthreads();
    m = fmaxf(fmaxf(red[0], red[1]), fmaxf(red[2], red[3]));
    __syncthreads();
    float s = 0.f;
    #pragma unroll
    for (int j = 0; j < 8; ++j) { x[j] = __expf(x[j] - m); s += x[j]; }
    #pragma unroll
    for (int off = 32; off >= 1; off >>= 1) s += __shfl_xor(s, off, 64);
    if ((t & 63) == 0) red[t >> 6] = s;
    __syncthreads();
    s = red[0] + red[1] + red[2] + red[3];
    const float inv = 1.0f / s;
    bf16x8 o8;
    #pragma unroll
    for (int j = 0; j < 8; ++j) o8[j] = bfbits(x[j] * inv);
    *(bf16x8*)(p + t * 8) = o8;
}

// ---------------------------------------------------------------------------
extern "C" void kernel_launch(void* const* d_in, const int* in_sizes, int n_in,
                              void* d_out, int out_size, void* d_ws, size_t ws_size,
                              hipStream_t stream) {
    (void)in_sizes; (void)n_in; (void)out_size; (void)ws_size;
    const float* text = (const float*)d_in[0];
    const float* adj  = (const float*)d_in[1];
    const float* Wq   = (const float*)d_in[2];
    const float* bq   = (const float*)d_in[3];
    const float* Wk   = (const float*)d_in[4];
    const float* bk   = (const float*)d_in[5];
    const float* Wv   = (const float*)d_in[6];
    const float* bv   = (const float*)d_in[7];

    float* out0 = (float*)d_out;                 // output [B,N,D]
    float* out1 = out0 + (size_t)BATCH * ND;     // new_adj [B,N,N]

    bf16* w = (bf16*)d_ws;
    bf16* adjT = w;  w += BATCH * NN;
    bf16* qb   = w;  w += BATCH * ND;
    bf16* kb   = w;  w += BATCH * ND;
    bf16* vTb  = w;  w += BATCH * ND;   // [B][D][N]
    bf16* attn = w;  w += BATCH * NN;   // scores, then softmax in place
    bf16* nadj = w;  w += BATCH * NN;

    transpose_adj_kernel<<<dim3(32, 32, BATCH), 256, 0, stream>>>(adj, adjT);
    qkv_kernel<<<dim3(BATCH * SEQ / 16), 256, 0, stream>>>(
        text, Wq, bq, Wk, bk, Wv, bv, qb, kb, vTb);
    // scores = (q @ k^T) / 16  -> bf16
    gemm_bt<128, 128, 2, 2><<<dim3(16, 16, BATCH), 256, 0, stream>>>(
        qb, kb, nullptr, attn, SEQ, SEQ, DIM,
        (long long)ND, (long long)ND, 0, (long long)NN, 1.0f / 16.0f);
    softmax_rows<<<dim3(BATCH * SEQ), 256, 0, stream>>>(attn);
    // new_adj = attn @ adj  -> fp32 (d_out) + bf16 (ws)
    gemm_bt<128, 128, 2, 2><<<dim3(16, 16, BATCH), 256, 0, stream>>>(
        attn, adjT, out1, nadj, SEQ, SEQ, SEQ,
        (long long)NN, (long long)NN, (long long)NN, (long long)NN, 1.0f);
    // output = new_adj @ v  -> fp32 (d_out); 128x64 tile => 512 blocks
    gemm_bt<128, 64, 4, 1><<<dim3(16, 4, BATCH), 256, 0, stream>>>(
        nadj, vTb, out0, nullptr, SEQ, DIM, SEQ,
        (long long)NN, (long long)ND, (long long)ND, 0, 1.0f);
}